// Round 1
// baseline (78.277 us; speedup 1.0000x reference)
//
#include <hip/hip_runtime.h>
#include <math.h>

#define H 64
#define W 64
#define C 256
#define NB 2
#define SS 32
#define HW (H*W)
#define EPS_L 1e-3

// ---------------- Kernel 1: [N,C,H,W] -> [N,H,W,C] transpose (both feats) ----
__global__ __launch_bounds__(256) void transpose_kernel(
    const float* __restrict__ feat1, const float* __restrict__ feat2,
    float* __restrict__ f1t, float* __restrict__ f2t) {
  __shared__ float tile[32][33];
  int z = blockIdx.z;                       // 0,1: feat1 n=0,1 ; 2,3: feat2 n=0,1
  const float* src = (z < NB ? feat1 : feat2) + (size_t)(z & 1) * (C * HW);
  float*       dst = (z < NB ? f1t   : f2t  ) + (size_t)(z & 1) * (C * HW);
  int p0 = blockIdx.x * 32;                 // spatial base (h*W+w)
  int c0 = blockIdx.y * 32;                 // channel base
  int tx = threadIdx.x, ty = threadIdx.y;   // block (32,8)
#pragma unroll
  for (int j = 0; j < 4; ++j) {
    int cc = c0 + ty + j * 8;
    tile[ty + j * 8][tx] = src[(size_t)cc * HW + p0 + tx];
  }
  __syncthreads();
#pragma unroll
  for (int j = 0; j < 4; ++j) {
    int pp = p0 + ty + j * 8;
    dst[(size_t)pp * C + c0 + tx] = tile[tx][ty + j * 8];
  }
}

// ---------------- Kernel 2: fundamental matrix per batch (fp64) --------------
__global__ void fmat_kernel(const float* __restrict__ P1f,
                            const float* __restrict__ P2f,
                            double* __restrict__ Fout) {
  int n = threadIdx.x;
  if (n >= NB) return;
  double p1[3][4], p2[3][4];
  for (int i = 0; i < 3; ++i)
    for (int j = 0; j < 4; ++j) {
      p1[i][j] = (double)P1f[n * 12 + i * 4 + j];
      p2[i][j] = (double)P2f[n * 12 + i * 4 + j];
    }
  // A = P1 P1^T (3x3), invert via adjugate
  double A[3][3];
  for (int i = 0; i < 3; ++i)
    for (int j = 0; j < 3; ++j) {
      double s = 0;
      for (int k = 0; k < 4; ++k) s += p1[i][k] * p1[j][k];
      A[i][j] = s;
    }
  double det = A[0][0] * (A[1][1] * A[2][2] - A[1][2] * A[2][1])
             - A[0][1] * (A[1][0] * A[2][2] - A[1][2] * A[2][0])
             + A[0][2] * (A[1][0] * A[2][1] - A[1][1] * A[2][0]);
  double id = 1.0 / det;
  double Ai[3][3];
  Ai[0][0] = (A[1][1] * A[2][2] - A[1][2] * A[2][1]) * id;
  Ai[0][1] = (A[0][2] * A[2][1] - A[0][1] * A[2][2]) * id;
  Ai[0][2] = (A[0][1] * A[1][2] - A[0][2] * A[1][1]) * id;
  Ai[1][0] = (A[1][2] * A[2][0] - A[1][0] * A[2][2]) * id;
  Ai[1][1] = (A[0][0] * A[2][2] - A[0][2] * A[2][0]) * id;
  Ai[1][2] = (A[0][2] * A[1][0] - A[0][0] * A[1][2]) * id;
  Ai[2][0] = (A[1][0] * A[2][1] - A[1][1] * A[2][0]) * id;
  Ai[2][1] = (A[0][1] * A[2][0] - A[0][0] * A[2][1]) * id;
  Ai[2][2] = (A[0][0] * A[1][1] - A[0][1] * A[1][0]) * id;
  // P1inv = P1^T * Ai (4x3)
  double Pi[4][3];
  for (int i = 0; i < 4; ++i)
    for (int j = 0; j < 3; ++j) {
      double s = 0;
      for (int k = 0; k < 3; ++k) s += p1[k][i] * Ai[k][j];
      Pi[i][j] = s;
    }
  // M = P2 @ P1inv (3x3)
  double M[3][3];
  for (int i = 0; i < 3; ++i)
    for (int j = 0; j < 3; ++j) {
      double s = 0;
      for (int k = 0; k < 4; ++k) s += p2[i][k] * Pi[k][j];
      M[i][j] = s;
    }
  // null vector of P1 = 4D cross product of its rows (sign/scale irrelevant)
  double nv[4];
  {
    auto det3 = [&](int ca, int cb, int cc) {
      return p1[0][ca] * (p1[1][cb] * p1[2][cc] - p1[1][cc] * p1[2][cb])
           - p1[0][cb] * (p1[1][ca] * p1[2][cc] - p1[1][cc] * p1[2][ca])
           + p1[0][cc] * (p1[1][ca] * p1[2][cb] - p1[1][cb] * p1[2][ca]);
    };
    nv[0] =  det3(1, 2, 3);
    nv[1] = -det3(0, 2, 3);
    nv[2] =  det3(0, 1, 3);
    nv[3] = -det3(0, 1, 2);
  }
  double nn = sqrt(nv[0]*nv[0] + nv[1]*nv[1] + nv[2]*nv[2] + nv[3]*nv[3]);
  for (int i = 0; i < 4; ++i) nv[i] /= nn;
  double e2[3];
  for (int i = 0; i < 3; ++i) {
    double s = 0;
    for (int j = 0; j < 4; ++j) s += p2[i][j] * nv[j];
    e2[i] = s;
  }
  // F = skew(e2) @ M
  for (int j = 0; j < 3; ++j) {
    Fout[n * 9 + 0 * 3 + j] = -e2[2] * M[1][j] + e2[1] * M[2][j];
    Fout[n * 9 + 1 * 3 + j] =  e2[2] * M[0][j] - e2[0] * M[2][j];
    Fout[n * 9 + 2 * 3 + j] = -e2[1] * M[0][j] + e2[0] * M[1][j];
  }
}

// ---------------- Kernel 3: per-pixel epipolar sample + online softmax -------
__global__ __launch_bounds__(256) void epi_main(
    const float* __restrict__ f1t, const float* __restrict__ f2t,
    const double* __restrict__ Fd, float* __restrict__ out) {
  const int tid  = threadIdx.x;
  const int lane = tid & 63;
  const int wave = tid >> 6;
  const int pix  = blockIdx.x * 4 + wave;   // 0..N*H*W-1
  const int n = pix >> 12;                  // / (H*W)
  const int p = pix & (HW - 1);
  const int h = p >> 6, w = p & (W - 1);

  // --- wave-uniform: epipolar line + endpoints (fp64) ---
  const double* F = Fd + n * 9;
  const double X = w * 4.0 + 1.5;           // pix2coord
  const double Y = h * 4.0 + 1.5;
  const double a = F[0] * X + F[1] * Y + F[2];
  const double b = F[3] * X + F[4] * Y + F[5];
  const double c = F[6] * X + F[7] * Y + F[8];
  const double a_s = (fabs(a) < EPS_L) ? EPS_L : a;
  const double b_s = (fabs(b) < EPS_L) ? EPS_L : b;
  const double xmin = 1.5, xmax = 253.5, ymin = 1.5, ymax = 253.5, tol = 0.01;
  double cx[4], cy[4];
  cx[0] = xmin;  cy[0] = -(c + a * xmin) / b_s;
  cx[1] = xmax;  cy[1] = -(c + a * xmax) / b_s;
  cx[2] = -(c + b * ymin) / a_s;  cy[2] = ymin;
  cx[3] = -(c + b * ymax) / a_s;  cy[3] = ymax;
  bool valid[4];
#pragma unroll
  for (int i = 0; i < 4; ++i)
    valid[i] = (cx[i] >= xmin - tol) && (cx[i] <= xmax + tol) &&
               (cy[i] >= ymin - tol) && (cy[i] <= ymax + tol);
#pragma unroll
  for (int i = 0; i < 4; ++i)
    if (!valid[i]) { cx[i] = xmin - 10000.0; cy[i] = ymin - 10000.0; }
  int pk0 = -1, pk1 = -1;
#pragma unroll
  for (int i = 0; i < 4; ++i)
    if (valid[i]) { if (pk0 < 0) pk0 = i; else if (pk1 < 0) pk1 = i; }
#pragma unroll
  for (int i = 0; i < 4; ++i)
    if (!valid[i]) { if (pk0 < 0) pk0 = i; else if (pk1 < 0) pk1 = i; }
  const double sx = (cx[pk0] - xmin) / (xmax - xmin) * 2.0 - 1.0;
  const double sy = (cy[pk0] - ymin) / (ymax - ymin) * 2.0 - 1.0;
  const double ex = (cx[pk1] - xmin) / (xmax - xmin) * 2.0 - 1.0;
  const double ey = (cy[pk1] - ymin) / (ymax - ymin) * 2.0 - 1.0;

  // --- per-lane: 4 channels as float4 ---
  const float* f2b = f2t + (size_t)n * HW * C;
  const float4 f1v = *(const float4*)(f1t + (size_t)n * HW * C + (size_t)p * C + lane * 4);

  float m = -INFINITY, l = 0.f;
  float4 acc = {0.f, 0.f, 0.f, 0.f};
  for (int s = 0; s < SS; ++s) {
    const double t = (double)s / (SS - 1);
    const float gx = (float)(sx + t * (ex - sx));
    const float gy = (float)(sy + t * (ey - sy));
    const float x = (gx + 1.f) * 0.5f * (W - 1);
    const float y = (gy + 1.f) * 0.5f * (H - 1);
    const float x0f = floorf(x), y0f = floorf(y);
    const float wx = x - x0f, wy = y - y0f;
    const int x0 = (int)x0f, y0 = (int)y0f;
    const int x1 = x0 + 1, y1 = y0 + 1;
    const bool bx0 = (x0 >= 0) & (x0 < W), bx1 = (x1 >= 0) & (x1 < W);
    const bool by0 = (y0 >= 0) & (y0 < H), by1 = (y1 >= 0) & (y1 < H);
    const int xc0 = min(max(x0, 0), W - 1), xc1 = min(max(x1, 0), W - 1);
    const int yc0 = min(max(y0, 0), H - 1), yc1 = min(max(y1, 0), H - 1);
    const float w00 = (1.f - wy) * (1.f - wx) * (float)(bx0 && by0);
    const float w01 = (1.f - wy) * wx         * (float)(bx1 && by0);
    const float w10 = wy * (1.f - wx)         * (float)(bx0 && by1);
    const float w11 = wy * wx                 * (float)(bx1 && by1);
    const float4 v00 = ((const float4*)(f2b + (size_t)(yc0 * W + xc0) * C))[lane];
    const float4 v01 = ((const float4*)(f2b + (size_t)(yc0 * W + xc1) * C))[lane];
    const float4 v10 = ((const float4*)(f2b + (size_t)(yc1 * W + xc0) * C))[lane];
    const float4 v11 = ((const float4*)(f2b + (size_t)(yc1 * W + xc1) * C))[lane];
    float4 v;
    v.x = w00 * v00.x + w01 * v01.x + w10 * v10.x + w11 * v11.x;
    v.y = w00 * v00.y + w01 * v01.y + w10 * v10.y + w11 * v11.y;
    v.z = w00 * v00.z + w01 * v01.z + w10 * v10.z + w11 * v11.z;
    v.w = w00 * v00.w + w01 * v01.w + w10 * v10.w + w11 * v11.w;
    float part = f1v.x * v.x + f1v.y * v.y + f1v.z * v.z + f1v.w * v.w;
#pragma unroll
    for (int off = 32; off >= 1; off >>= 1)
      part += __shfl_xor(part, off, 64);
    const float logit = part;
    const float mn = fmaxf(m, logit);
    const float sc = __expf(m - mn);
    const float e  = __expf(logit - mn);
    l = l * sc + e;
    acc.x = acc.x * sc + e * v.x;
    acc.y = acc.y * sc + e * v.y;
    acc.z = acc.z * sc + e * v.z;
    acc.w = acc.w * sc + e * v.w;
    m = mn;
  }
  const float inv = 1.0f / l;
  const size_t ob = (size_t)n * C * HW + (size_t)p;
  const int cb = lane * 4;
  out[ob + (size_t)(cb + 0) * HW] = acc.x * inv;
  out[ob + (size_t)(cb + 1) * HW] = acc.y * inv;
  out[ob + (size_t)(cb + 2) * HW] = acc.z * inv;
  out[ob + (size_t)(cb + 3) * HW] = acc.w * inv;
}

extern "C" void kernel_launch(void* const* d_in, const int* in_sizes, int n_in,
                              void* d_out, int out_size, void* d_ws, size_t ws_size,
                              hipStream_t stream) {
  const float* feat1 = (const float*)d_in[0];
  const float* feat2 = (const float*)d_in[1];
  const float* P1 = (const float*)d_in[2];
  const float* P2 = (const float*)d_in[3];
  float* out = (float*)d_out;

  char* ws = (char*)d_ws;
  const size_t feat_bytes = (size_t)NB * HW * C * sizeof(float);  // 8 MB
  float*  f2t = (float*)ws;
  float*  f1t = (float*)(ws + feat_bytes);
  double* Fd  = (double*)(ws + 2 * feat_bytes);

  transpose_kernel<<<dim3(HW / 32, C / 32, 2 * NB), dim3(32, 8), 0, stream>>>(
      feat1, feat2, f1t, f2t);
  fmat_kernel<<<1, 64, 0, stream>>>(P1, P2, Fd);
  epi_main<<<NB * HW / 4, 256, 0, stream>>>(f1t, f2t, Fd, out);
}

// Round 2
// 56.756 us; speedup vs baseline: 1.3792x; 1.3792x over previous
//
#include <hip/hip_runtime.h>
#include <math.h>

#define H 64
#define W 64
#define C 256
#define NB 2
#define SS 32
#define HW (H*W)

// ---------------- Kernel 1: [N,C,H,W] -> [N,H,W,C] transpose (both feats) ----
__global__ __launch_bounds__(256) void transpose_kernel(
    const float* __restrict__ feat1, const float* __restrict__ feat2,
    float* __restrict__ f1t, float* __restrict__ f2t) {
  __shared__ float tile[32][33];
  int z = blockIdx.z;                       // 0,1: feat1 n=0,1 ; 2,3: feat2 n=0,1
  const float* src = (z < NB ? feat1 : feat2) + (size_t)(z & 1) * (C * HW);
  float*       dst = (z < NB ? f1t   : f2t  ) + (size_t)(z & 1) * (C * HW);
  int p0 = blockIdx.x * 32;                 // spatial base (h*W+w)
  int c0 = blockIdx.y * 32;                 // channel base
  int tx = threadIdx.x, ty = threadIdx.y;   // block (32,8)
#pragma unroll
  for (int j = 0; j < 4; ++j) {
    int cc = c0 + ty + j * 8;
    tile[ty + j * 8][tx] = src[(size_t)cc * HW + p0 + tx];
  }
  __syncthreads();
#pragma unroll
  for (int j = 0; j < 4; ++j) {
    int pp = p0 + ty + j * 8;
    dst[(size_t)pp * C + c0 + tx] = tile[tx][ty + j * 8];
  }
}

// ---------------- Kernel 2: fundamental matrix per batch (fp64) --------------
__global__ void fmat_kernel(const float* __restrict__ P1f,
                            const float* __restrict__ P2f,
                            double* __restrict__ Fout) {
  int n = threadIdx.x;
  if (n >= NB) return;
  double p1[3][4], p2[3][4];
  for (int i = 0; i < 3; ++i)
    for (int j = 0; j < 4; ++j) {
      p1[i][j] = (double)P1f[n * 12 + i * 4 + j];
      p2[i][j] = (double)P2f[n * 12 + i * 4 + j];
    }
  double A[3][3];
  for (int i = 0; i < 3; ++i)
    for (int j = 0; j < 3; ++j) {
      double s = 0;
      for (int k = 0; k < 4; ++k) s += p1[i][k] * p1[j][k];
      A[i][j] = s;
    }
  double det = A[0][0] * (A[1][1] * A[2][2] - A[1][2] * A[2][1])
             - A[0][1] * (A[1][0] * A[2][2] - A[1][2] * A[2][0])
             + A[0][2] * (A[1][0] * A[2][1] - A[1][1] * A[2][0]);
  double id = 1.0 / det;
  double Ai[3][3];
  Ai[0][0] = (A[1][1] * A[2][2] - A[1][2] * A[2][1]) * id;
  Ai[0][1] = (A[0][2] * A[2][1] - A[0][1] * A[2][2]) * id;
  Ai[0][2] = (A[0][1] * A[1][2] - A[0][2] * A[1][1]) * id;
  Ai[1][0] = (A[1][2] * A[2][0] - A[1][0] * A[2][2]) * id;
  Ai[1][1] = (A[0][0] * A[2][2] - A[0][2] * A[2][0]) * id;
  Ai[1][2] = (A[0][2] * A[1][0] - A[0][0] * A[1][2]) * id;
  Ai[2][0] = (A[1][0] * A[2][1] - A[1][1] * A[2][0]) * id;
  Ai[2][1] = (A[0][1] * A[2][0] - A[0][0] * A[2][1]) * id;
  Ai[2][2] = (A[0][0] * A[1][1] - A[0][1] * A[1][0]) * id;
  double Pi[4][3];
  for (int i = 0; i < 4; ++i)
    for (int j = 0; j < 3; ++j) {
      double s = 0;
      for (int k = 0; k < 3; ++k) s += p1[k][i] * Ai[k][j];
      Pi[i][j] = s;
    }
  double M[3][3];
  for (int i = 0; i < 3; ++i)
    for (int j = 0; j < 3; ++j) {
      double s = 0;
      for (int k = 0; k < 4; ++k) s += p2[i][k] * Pi[k][j];
      M[i][j] = s;
    }
  double nv[4];
  {
    auto det3 = [&](int ca, int cb, int cc) {
      return p1[0][ca] * (p1[1][cb] * p1[2][cc] - p1[1][cc] * p1[2][cb])
           - p1[0][cb] * (p1[1][ca] * p1[2][cc] - p1[1][cc] * p1[2][ca])
           + p1[0][cc] * (p1[1][ca] * p1[2][cb] - p1[1][cb] * p1[2][ca]);
    };
    nv[0] =  det3(1, 2, 3);
    nv[1] = -det3(0, 2, 3);
    nv[2] =  det3(0, 1, 3);
    nv[3] = -det3(0, 1, 2);
  }
  double nn = sqrt(nv[0]*nv[0] + nv[1]*nv[1] + nv[2]*nv[2] + nv[3]*nv[3]);
  for (int i = 0; i < 4; ++i) nv[i] /= nn;
  double e2[3];
  for (int i = 0; i < 3; ++i) {
    double s = 0;
    for (int j = 0; j < 4; ++j) s += p2[i][j] * nv[j];
    e2[i] = s;
  }
  for (int j = 0; j < 3; ++j) {
    Fout[n * 9 + 0 * 3 + j] = -e2[2] * M[1][j] + e2[1] * M[2][j];
    Fout[n * 9 + 1 * 3 + j] =  e2[2] * M[0][j] - e2[0] * M[2][j];
    Fout[n * 9 + 2 * 3 + j] = -e2[1] * M[0][j] + e2[0] * M[1][j];
  }
}

// ------- Kernel 3: 4 pixels/wave, 16 lanes/pixel, 16 channels/lane ----------
__global__ __launch_bounds__(256) void epi_main(
    const float* __restrict__ f1t, const float* __restrict__ f2t,
    const double* __restrict__ Fd, float* __restrict__ out) {
  const int tid  = threadIdx.x;
  const int lane = tid & 63;
  const int wv   = tid >> 6;
  const int grp  = lane >> 4;               // pixel within wave (0..3)
  const int cl   = lane & 15;               // channel-group lane (0..15)
  const int pix  = blockIdx.x * 16 + wv * 4 + grp;
  const int n = pix >> 12;
  const int p = pix & (HW - 1);
  const int h = p >> 6, w = p & (W - 1);

  // --- epipolar line + endpoint pick, fp32 (matches reference dtype) ---
  const double* Fdp = Fd + n * 9;
  const float F0 = (float)Fdp[0], F1 = (float)Fdp[1], F2 = (float)Fdp[2];
  const float F3 = (float)Fdp[3], F4 = (float)Fdp[4], F5 = (float)Fdp[5];
  const float F6 = (float)Fdp[6], F7 = (float)Fdp[7], F8 = (float)Fdp[8];
  const float X = w * 4.0f + 1.5f;          // pix2coord
  const float Y = h * 4.0f + 1.5f;
  const float a = F0 * X + F1 * Y + F2;
  const float b = F3 * X + F4 * Y + F5;
  const float c = F6 * X + F7 * Y + F8;
  const float a_s = (fabsf(a) < 1e-3f) ? 1e-3f : a;
  const float b_s = (fabsf(b) < 1e-3f) ? 1e-3f : b;
  const float xmin = 1.5f, xmax = 253.5f, ymin = 1.5f, ymax = 253.5f, tol = 0.01f;
  float cx[4], cy[4];
  cx[0] = xmin;  cy[0] = -(c + a * xmin) / b_s;
  cx[1] = xmax;  cy[1] = -(c + a * xmax) / b_s;
  cx[2] = -(c + b * ymin) / a_s;  cy[2] = ymin;
  cx[3] = -(c + b * ymax) / a_s;  cy[3] = ymax;
  bool valid[4];
#pragma unroll
  for (int i = 0; i < 4; ++i)
    valid[i] = (cx[i] >= xmin - tol) && (cx[i] <= xmax + tol) &&
               (cy[i] >= ymin - tol) && (cy[i] <= ymax + tol);
#pragma unroll
  for (int i = 0; i < 4; ++i)
    if (!valid[i]) { cx[i] = xmin - 10000.0f; cy[i] = ymin - 10000.0f; }
  int pk0 = -1, pk1 = -1;
#pragma unroll
  for (int i = 0; i < 4; ++i)
    if (valid[i]) { if (pk0 < 0) pk0 = i; else if (pk1 < 0) pk1 = i; }
#pragma unroll
  for (int i = 0; i < 4; ++i)
    if (!valid[i]) { if (pk0 < 0) pk0 = i; else if (pk1 < 0) pk1 = i; }
  // endpoints directly in destination-pixel coords:
  // nx=(px-xmin)/(xmax-xmin)*2-1 ; x=(nx+1)*0.5*(W-1)  ==>  x=(px-1.5)*0.25
  const float x0p = (cx[pk0] - 1.5f) * 0.25f;
  const float y0p = (cy[pk0] - 1.5f) * 0.25f;
  const float pdx = (cx[pk1] - 1.5f) * 0.25f - x0p;
  const float pdy = (cy[pk1] - 1.5f) * 0.25f - y0p;

  // --- per-lane: 16 channels as 4x float4 (channels 64*j + cl*4 + i) ---
  const float* f1b = f1t + ((size_t)n * HW + p) * C + cl * 4;
  const float4 f1v0 = *(const float4*)(f1b +   0);
  const float4 f1v1 = *(const float4*)(f1b +  64);
  const float4 f1v2 = *(const float4*)(f1b + 128);
  const float4 f1v3 = *(const float4*)(f1b + 192);
  const float* f2b = f2t + (size_t)n * HW * C + cl * 4;

  float m = -INFINITY, l = 0.f;
  float4 acc0 = {0,0,0,0}, acc1 = {0,0,0,0}, acc2 = {0,0,0,0}, acc3 = {0,0,0,0};

#pragma unroll 2
  for (int s = 0; s < SS; ++s) {
    const float t = (float)s * (1.0f / 31.0f);
    const float x = fmaf(t, pdx, x0p);
    const float y = fmaf(t, pdy, y0p);
    const float xf = floorf(x), yf = floorf(y);
    const float wx = x - xf, wy = y - yf;
    const int x0 = (int)xf, y0 = (int)yf;
    const int x1 = x0 + 1, y1 = y0 + 1;
    const bool bx0 = ((unsigned)x0 < W), bx1 = ((unsigned)x1 < W);
    const bool by0 = ((unsigned)y0 < H), by1 = ((unsigned)y1 < H);
    const int xc0 = min(max(x0, 0), W - 1), xc1 = min(max(x1, 0), W - 1);
    const int yc0 = min(max(y0, 0), H - 1), yc1 = min(max(y1, 0), H - 1);
    const float u0 = 1.f - wx, v0 = 1.f - wy;
    const float w00 = v0 * u0 * (float)(bx0 & by0);
    const float w01 = v0 * wx * (float)(bx1 & by0);
    const float w10 = wy * u0 * (float)(bx0 & by1);
    const float w11 = wy * wx * (float)(bx1 & by1);
    const float* p00 = f2b + (size_t)((yc0 * W + xc0) * C);
    const float* p01 = f2b + (size_t)((yc0 * W + xc1) * C);
    const float* p10 = f2b + (size_t)((yc1 * W + xc0) * C);
    const float* p11 = f2b + (size_t)((yc1 * W + xc1) * C);

    float part = 0.f;
    float4 q0, q1, q2, q3;
#define CHUNK(J, OFF, F1V, Q)                                            \
    {                                                                    \
      const float4 s00 = *(const float4*)(p00 + OFF);                    \
      const float4 s01 = *(const float4*)(p01 + OFF);                    \
      const float4 s10 = *(const float4*)(p10 + OFF);                    \
      const float4 s11 = *(const float4*)(p11 + OFF);                    \
      Q.x = w00*s00.x + w01*s01.x + w10*s10.x + w11*s11.x;               \
      Q.y = w00*s00.y + w01*s01.y + w10*s10.y + w11*s11.y;               \
      Q.z = w00*s00.z + w01*s01.z + w10*s10.z + w11*s11.z;               \
      Q.w = w00*s00.w + w01*s01.w + w10*s10.w + w11*s11.w;               \
      part += F1V.x*Q.x + F1V.y*Q.y + F1V.z*Q.z + F1V.w*Q.w;             \
    }
    CHUNK(0,   0, f1v0, q0)
    CHUNK(1,  64, f1v1, q1)
    CHUNK(2, 128, f1v2, q2)
    CHUNK(3, 192, f1v3, q3)
#undef CHUNK
    // reduce across the 16 lanes of this pixel's group
    part += __shfl_xor(part, 1);
    part += __shfl_xor(part, 2);
    part += __shfl_xor(part, 4);
    part += __shfl_xor(part, 8);

    if (part > m) {                 // max grew: rescale (rare after warmup)
      const float sc = __expf(m - part);
      l *= sc;
      acc0.x *= sc; acc0.y *= sc; acc0.z *= sc; acc0.w *= sc;
      acc1.x *= sc; acc1.y *= sc; acc1.z *= sc; acc1.w *= sc;
      acc2.x *= sc; acc2.y *= sc; acc2.z *= sc; acc2.w *= sc;
      acc3.x *= sc; acc3.y *= sc; acc3.z *= sc; acc3.w *= sc;
      m = part;
    }
    const float e = __expf(part - m);
    l += e;
    acc0.x = fmaf(e, q0.x, acc0.x); acc0.y = fmaf(e, q0.y, acc0.y);
    acc0.z = fmaf(e, q0.z, acc0.z); acc0.w = fmaf(e, q0.w, acc0.w);
    acc1.x = fmaf(e, q1.x, acc1.x); acc1.y = fmaf(e, q1.y, acc1.y);
    acc1.z = fmaf(e, q1.z, acc1.z); acc1.w = fmaf(e, q1.w, acc1.w);
    acc2.x = fmaf(e, q2.x, acc2.x); acc2.y = fmaf(e, q2.y, acc2.y);
    acc2.z = fmaf(e, q2.z, acc2.z); acc2.w = fmaf(e, q2.w, acc2.w);
    acc3.x = fmaf(e, q3.x, acc3.x); acc3.y = fmaf(e, q3.y, acc3.y);
    acc3.z = fmaf(e, q3.z, acc3.z); acc3.w = fmaf(e, q3.w, acc3.w);
  }

  const float inv = 1.0f / l;
  float* ob = out + (size_t)n * C * HW + p + (size_t)(cl * 4) * HW;
#define STORE(J, ACC)                                    \
  ob[(size_t)(64*J + 0) * HW] = ACC.x * inv;             \
  ob[(size_t)(64*J + 1) * HW] = ACC.y * inv;             \
  ob[(size_t)(64*J + 2) * HW] = ACC.z * inv;             \
  ob[(size_t)(64*J + 3) * HW] = ACC.w * inv;
  STORE(0, acc0) STORE(1, acc1) STORE(2, acc2) STORE(3, acc3)
#undef STORE
}

extern "C" void kernel_launch(void* const* d_in, const int* in_sizes, int n_in,
                              void* d_out, int out_size, void* d_ws, size_t ws_size,
                              hipStream_t stream) {
  const float* feat1 = (const float*)d_in[0];
  const float* feat2 = (const float*)d_in[1];
  const float* P1 = (const float*)d_in[2];
  const float* P2 = (const float*)d_in[3];
  float* out = (float*)d_out;

  char* ws = (char*)d_ws;
  const size_t feat_bytes = (size_t)NB * HW * C * sizeof(float);  // 8 MB
  float*  f2t = (float*)ws;
  float*  f1t = (float*)(ws + feat_bytes);
  double* Fd  = (double*)(ws + 2 * feat_bytes);

  fmat_kernel<<<1, 64, 0, stream>>>(P1, P2, Fd);
  transpose_kernel<<<dim3(HW / 32, C / 32, 2 * NB), dim3(32, 8), 0, stream>>>(
      feat1, feat2, f1t, f2t);
  epi_main<<<NB * HW / 16, 256, 0, stream>>>(f1t, f2t, Fd, out);
}